// Round 9
// baseline (281.166 us; speedup 1.0000x reference)
//
#include <hip/hip_runtime.h>
#include <hip/hip_bf16.h>
#include <stdint.h>

// Problem constants
constexpr int S_ = 2048, H_ = 32, G_ = 8, HPG_ = 4, D_ = 128, MODEL_ = 4096;

typedef __attribute__((ext_vector_type(4))) float f32x4;
typedef __attribute__((ext_vector_type(16))) float f32x16;
typedef __attribute__((ext_vector_type(8))) short bf16x8;
typedef __attribute__((ext_vector_type(4))) short bf16x4;

__device__ inline unsigned short f2bf(float f) {
  unsigned u = __float_as_uint(f);
  u += 0x7FFFu + ((u >> 16) & 1u);   // round-to-nearest-even
  return (unsigned short)(u >> 16);
}

__device__ inline unsigned cvt_pk_bf16(float lo, float hi) {
  unsigned r;
  asm("v_cvt_pk_bf16_f32 %0, %1, %2" : "=v"(r) : "v"(lo), "v"(hi));
  return r;
}

__device__ inline void gload_lds16(const void* g, void* l) {
  __builtin_amdgcn_global_load_lds(
      (const __attribute__((address_space(1))) unsigned int*)g,
      (__attribute__((address_space(3))) unsigned int*)l,
      16, 0, 0);
}

// ---------------- w_out f32 -> bf16 (runs AFTER attn; aliases k/v region) ---
__global__ __launch_bounds__(256) void cvt_f32_to_bf16(
    const float* __restrict__ in, unsigned short* __restrict__ out, int n4) {
  int i = blockIdx.x * 256 + threadIdx.x;
  if (i < n4) {
    float4 v = reinterpret_cast<const float4*>(in)[i];
    bf16x4 o;
    o[0] = f2bf(v.x); o[1] = f2bf(v.y); o[2] = f2bf(v.z); o[3] = f2bf(v.w);
    reinterpret_cast<bf16x4*>(out)[i] = o;
  }
}

// ---------------- K: [S][G][D] f32 -> [G][S][D] bf16 ----------------
__global__ __launch_bounds__(256) void cvt_k_kernel(
    const float* __restrict__ in, unsigned short* __restrict__ out) {
  int i = blockIdx.x * 256 + threadIdx.x;   // over S*G*D/4
  int d4 = i & 31, g = (i >> 5) & 7, s = i >> 8;
  float4 v = reinterpret_cast<const float4*>(in)[i];
  bf16x4 o;
  o[0] = f2bf(v.x); o[1] = f2bf(v.y); o[2] = f2bf(v.z); o[3] = f2bf(v.w);
  reinterpret_cast<bf16x4*>(out)[(g * S_ + s) * 32 + d4] = o;
}

// ---------------- V: [S][G][D] f32 -> [G][D][S] bf16 (transpose) -----------
__global__ __launch_bounds__(256) void cvt_v_kernel(
    const float* __restrict__ in, unsigned short* __restrict__ out) {
  __shared__ float t[64][33];
  int s0 = blockIdx.x * 64, d0 = blockIdx.y * 32, g = blockIdx.z;
  int tid = threadIdx.x;
#pragma unroll
  for (int p = 0; p < 2; ++p) {
    int idx = p * 256 + tid;
    int s = idx >> 3, dq = (idx & 7) * 4;
    float4 v = *reinterpret_cast<const float4*>(
        in + ((size_t)(s0 + s) * G_ + g) * D_ + d0 + dq);
    t[s][dq] = v.x; t[s][dq + 1] = v.y; t[s][dq + 2] = v.z; t[s][dq + 3] = v.w;
  }
  __syncthreads();
  int d = tid >> 3, sq = (tid & 7) * 8;
  bf16x8 o;
#pragma unroll
  for (int j = 0; j < 8; ++j) o[j] = f2bf(t[sq + j][d]);
  *reinterpret_cast<bf16x8*>(out + ((size_t)g * D_ + d0 + d) * S_ + s0 + sq) = o;
}

// ---------------- flash attention, 8 waves, in-block KV-split ----------------
// grid (S/128, H), 512 threads. Waves 0-3: kv [0,1024); waves 4-7: kv [1024,2048).
// Wave (w&3) owns q rows qt*128 + (w&3)*32. Per group: KVB=32 double-buffered,
// stage(t+1) issued BEFORE process(t), one vmcnt(0)+barrier per tile (T3-min).
// S^T = K·Q^T (A=K LDS, B=Q regs); O^T += Vt·P^T (A=Vt LDS, B=P via permlane).
// Finish: group1 -> partial O f32 + (m,l) in LDS; group0 merges (exact f32).
// K tile [32 kv][128 d], swizzle (kv&15)<<4. V tile rows of 4 d x 64B packed
// into 256B, swizzle (R&7)<<4 -> PV reads 2-way (free).
constexpr int QB2 = 128, KVB = 32, NTG = 1024 / KVB;   // 32 tiles per group
constexpr float RTHR = 8.0f;   // defer-max threshold, log2 units

__global__ __launch_bounds__(512, 4) void attn32_kernel(
    const float* __restrict__ q, const unsigned short* __restrict__ kb,
    const unsigned short* __restrict__ vtb, unsigned short* __restrict__ aout) {
  // main: 2 groups x 2 bufs x 16KB = 64KB. epilogue: O1 f32 64KB + ml 1KB;
  // Ol (32KB) reuses [0,32KB) after merge. Total 65KB -> 2 blocks/CU.
  __shared__ __align__(16) char smem[66560];

  const int qt = blockIdx.x, h = blockIdx.y;
  const int g = h >> 2;   // HPG = 4
  const int tid = threadIdx.x, w = tid >> 6, lane = tid & 63;
  const int l31 = lane & 31, hi = lane >> 5;
  const int gsel = w >> 2, wq = w & 3;

  // ---- Q B-frags (scale * log2e folded in): qf[c] d = c*16 + hi*8 + e ----
  const float scale2 = 0.12751742354783493f;  // (1/sqrt(128)) * log2(e)
  bf16x8 qf[8];
  {
    const int qrow = qt * QB2 + wq * 32 + l31;
    const float* qp = q + ((size_t)qrow * H_ + h) * D_;
#pragma unroll
    for (int c = 0; c < 8; ++c) {
      const float* p0 = qp + c * 16 + hi * 8;
      float4 a = *(const float4*)p0;
      float4 b = *(const float4*)(p0 + 4);
      bf16x8 f;
      f[0] = f2bf(a.x * scale2); f[1] = f2bf(a.y * scale2);
      f[2] = f2bf(a.z * scale2); f[3] = f2bf(a.w * scale2);
      f[4] = f2bf(b.x * scale2); f[5] = f2bf(b.y * scale2);
      f[6] = f2bf(b.z * scale2); f[7] = f2bf(b.w * scale2);
      qf[c] = f;
    }
  }

  // ---- staging source precompute (pre-swizzled; linear LDS == swizzled) ----
  // K 8KB: phys p -> kv = p>>8, log col byte = (p&255) ^ ((kv&15)<<4)
  // V 8KB: phys p -> R = p>>8 (R = d>>2), il = (p&255) ^ ((R&7)<<4),
  //        d = R*4 + (il>>6), kv = (il&63)>>1
  int kvK[2], dK[2], dV[2], kvV[2];
#pragma unroll
  for (int j = 0; j < 2; ++j) {
    int p = (wq * 2 + j) * 1024 + lane * 16;
    int kvr = p >> 8;
    kvK[j] = kvr;
    dK[j] = ((p & 255) ^ ((kvr & 15) << 4)) >> 1;
    int R = p >> 8;
    int il = (p & 255) ^ ((R & 7) << 4);
    dV[j] = R * 4 + (il >> 6);
    kvV[j] = (il & 63) >> 1;
  }
  const unsigned short* kg = kb + (size_t)g * S_ * D_;
  const unsigned short* vg = vtb + (size_t)g * D_ * S_;
  const int kvbase = gsel * 1024;

  auto stage = [&](int t) {
    int kv0 = kvbase + t * KVB;
    char* base = smem + (gsel * 2 + (t & 1)) * 16384;
#pragma unroll
    for (int j = 0; j < 2; ++j) {
      gload_lds16(kg + (size_t)(kv0 + kvK[j]) * D_ + dK[j],
                  base + (wq * 2 + j) * 1024);
      gload_lds16(vg + (size_t)dV[j] * S_ + kv0 + kvV[j],
                  base + 8192 + (wq * 2 + j) * 1024);
    }
  };

  f32x16 of[4];
#pragma unroll
  for (int i = 0; i < 4; ++i) of[i] = (f32x16)0.f;
  float m = -1e30f, l = 0.f;

  // ---- prologue ----
  stage(0);
  asm volatile("s_waitcnt vmcnt(0)" ::: "memory");
  __builtin_amdgcn_s_barrier();

  // ---- main loop: stage(t+1) first, then compute(t); 1 barrier/tile ----
  for (int t = 0; t < NTG; ++t) {
    if (t + 1 < NTG) stage(t + 1);

    const char* Kd = smem + (gsel * 2 + (t & 1)) * 16384;
    const char* Vd = Kd + 8192;

    // ---- QK^T: S^T[kv][q], single accumulator (reg-lean; TLP feeds pipe) ----
    f32x16 sv = (f32x16)0.f;
    __builtin_amdgcn_s_setprio(1);
#pragma unroll
    for (int c = 0; c < 8; ++c) {
      unsigned off = (unsigned)(l31 * 256) +
                     (((unsigned)(c * 32 + hi * 16)) ^ ((unsigned)(l31 & 15) << 4));
      bf16x8 kf = *(const bf16x8*)(Kd + off);
      sv = __builtin_amdgcn_mfma_f32_32x32x16_bf16(kf, qf[c], sv, 0, 0, 0);
    }
    __builtin_amdgcn_s_setprio(0);
    // rows: kv = (r&3) + 8*(r>>2) + 4*hi; col q = l31

    // ---- online softmax (exp2 domain; tree reductions) ----
    float mx[8];
#pragma unroll
    for (int i = 0; i < 8; ++i) mx[i] = fmaxf(sv[i], sv[i + 8]);
#pragma unroll
    for (int i = 0; i < 4; ++i) mx[i] = fmaxf(mx[i], mx[i + 4]);
    float tmax = fmaxf(fmaxf(mx[0], mx[1]), fmaxf(mx[2], mx[3]));
    tmax = fmaxf(tmax, __shfl_xor(tmax, 32));
    if (__any(tmax > m + RTHR)) {
      float mnew = fmaxf(m, tmax);
      float alpha = __builtin_exp2f(m - mnew);
#pragma unroll
      for (int i = 0; i < 4; ++i)
#pragma unroll
        for (int r = 0; r < 16; ++r) of[i][r] *= alpha;
      l *= alpha;
      m = mnew;
    }
    float pv[16], ps[8];
#pragma unroll
    for (int r = 0; r < 16; ++r) pv[r] = __builtin_exp2f(sv[r] - m);
#pragma unroll
    for (int i = 0; i < 8; ++i) ps[i] = pv[i] + pv[i + 8];
#pragma unroll
    for (int i = 0; i < 4; ++i) ps[i] += ps[i + 4];
    float sum = (ps[0] + ps[1]) + (ps[2] + ps[3]);
    sum += __shfl_xor(sum, 32);
    l += sum;

    // ---- P -> B-frags: cvt_pk pairs, permlane32_swap gathers lows/highs ----
    unsigned pk[8];
#pragma unroll
    for (int b = 0; b < 8; ++b) pk[b] = cvt_pk_bf16(pv[2 * b], pv[2 * b + 1]);
    bf16x8 pf[2];
#pragma unroll
    for (int kc = 0; kc < 2; ++kc) {
      auto sA = __builtin_amdgcn_permlane32_swap(pk[kc * 4 + 0], pk[kc * 4 + 2],
                                                 false, false);
      auto sB = __builtin_amdgcn_permlane32_swap(pk[kc * 4 + 1], pk[kc * 4 + 3],
                                                 false, false);
      unsigned fr[4] = {(unsigned)sA[0], (unsigned)sB[0],
                        (unsigned)sA[1], (unsigned)sB[1]};
      __builtin_memcpy(&pf[kc], fr, 16);
    }

    // ---- PV: O^T[d][q] += Vt·P^T, 4 independent chains ----
    __builtin_amdgcn_s_setprio(1);
#pragma unroll
    for (int db = 0; db < 4; ++db) {
      int R = db * 8 + (l31 >> 2);
      unsigned lg = (unsigned)((l31 & 3) * 64);
#pragma unroll
      for (int kc = 0; kc < 2; ++kc) {
        unsigned off = (unsigned)(R * 256) +
                       ((lg + (unsigned)(kc * 32 + hi * 16)) ^ ((unsigned)(R & 7) << 4));
        bf16x8 vf = *(const bf16x8*)(Vd + off);
        of[db] = __builtin_amdgcn_mfma_f32_32x32x16_bf16(vf, pf[kc], of[db], 0, 0, 0);
      }
    }
    __builtin_amdgcn_s_setprio(0);

    asm volatile("s_waitcnt vmcnt(0)" ::: "memory");
    __builtin_amdgcn_s_barrier();
  }

  // ---- combine: group1 publishes partial O (f32) + (m,l); group0 merges ----
  float* O1 = (float*)smem;                    // 4 waves x 16KB = 64KB
  float* ml = (float*)(smem + 65536);          // [4 wq][32 q][2]
  if (w >= 4) {
    float* reg = O1 + (w - 4) * 4096;          // [128 d][32 q] f32
#pragma unroll
    for (int db = 0; db < 4; ++db)
#pragma unroll
      for (int r = 0; r < 16; ++r) {
        int dd = db * 32 + (r & 3) + 8 * (r >> 2) + 4 * hi;
        reg[dd * 32 + l31] = of[db][r];
      }
    if (!hi) { ml[wq * 64 + l31 * 2] = m; ml[wq * 64 + l31 * 2 + 1] = l; }
  }
  __syncthreads();
  float inv = 0.f;
  if (w < 4) {
    float m1 = ml[wq * 64 + l31 * 2], l1 = ml[wq * 64 + l31 * 2 + 1];
    float mf = fmaxf(m, m1);
    float a0 = __builtin_exp2f(m - mf), a1 = __builtin_exp2f(m1 - mf);
    inv = 1.0f / (l * a0 + l1 * a1);
    const float* reg = O1 + wq * 4096;
#pragma unroll
    for (int db = 0; db < 4; ++db)
#pragma unroll
      for (int r = 0; r < 16; ++r) {
        int dd = db * 32 + (r & 3) + 8 * (r >> 2) + 4 * hi;
        of[db][r] = of[db][r] * a0 + reg[dd * 32 + l31] * a1;
      }
  }
  __syncthreads();

  // ---- epilogue: normalize, transpose via LDS (Ol reuses [0,32KB)) ----
  unsigned short* Ol = (unsigned short*)smem;  // [128 q][128 d] bf16 = 32KB
  if (w < 4) {
    const int ql = wq * 32 + l31;
#pragma unroll
    for (int db = 0; db < 4; ++db)
#pragma unroll
      for (int rp = 0; rp < 8; ++rp) {
        int r0 = rp * 2;
        int d0 = db * 32 + (r0 & 3) + 8 * (r0 >> 2) + 4 * hi;
        unsigned pkv = cvt_pk_bf16(of[db][r0] * inv, of[db][r0 + 1] * inv);
        unsigned off = ((unsigned)(ql * 256 + d0 * 2)) ^ ((unsigned)(ql & 7) << 4);
        *(unsigned*)((char*)Ol + off) = pkv;
      }
  }
  __syncthreads();
  const size_t obase = ((size_t)qt * QB2) * MODEL_ + (size_t)h * D_;
#pragma unroll
  for (int pass = 0; pass < 4; ++pass) {
    int row = pass * 32 + (tid >> 4);
    int c = tid & 15;
    unsigned off = ((unsigned)(row * 256 + c * 16)) ^ ((unsigned)(row & 7) << 4);
    bf16x8 vv = *(const bf16x8*)((char*)Ol + off);
    *(bf16x8*)(aout + obase + (size_t)row * MODEL_ + c * 8) = vv;
  }
}

// ---------------- out-projection GEMM: C = A @ B^T + bias (m97 structure) ----
constexpr int BM = 128, BN = 128, BK = 64;

__global__ __launch_bounds__(256, 2) void gemm_bt_bias(
    const unsigned short* __restrict__ A, const unsigned short* __restrict__ B,
    const float* __restrict__ bias, float* __restrict__ C) {
  __shared__ unsigned short As[BM * BK];
  __shared__ unsigned short Bs[BN * BK];

  const int tid = threadIdx.x;
  const int w = tid >> 6, lane = tid & 63;
  const int wr = w >> 1, wc = w & 1;
  const int r16 = lane & 15, g4 = lane >> 4;
  const int row0 = blockIdx.y * BM, col0 = blockIdx.x * BN;

  f32x4 acc[4][4];
#pragma unroll
  for (int m = 0; m < 4; ++m)
#pragma unroll
    for (int n = 0; n < 4; ++n) acc[m][n] = (f32x4)0.f;

  for (int kt = 0; kt < MODEL_ / BK; ++kt) {
    const int k0 = kt * BK;
    __syncthreads();
#pragma unroll
    for (int j = 0; j < 4; ++j) {
      int chunk = w * 4 + j;
      int sb = chunk * 1024 + lane * 16;
      int srow = sb >> 7;
      int lb = sb ^ ((srow & 7) << 4);
      int kk = (lb & 127) >> 1;
      gload_lds16(A + (size_t)(row0 + srow) * MODEL_ + k0 + kk,
                  (char*)As + chunk * 1024);
      gload_lds16(B + (size_t)(col0 + srow) * MODEL_ + k0 + kk,
                  (char*)Bs + chunk * 1024);
    }
    asm volatile("s_waitcnt vmcnt(0)" ::: "memory");
    __syncthreads();

#pragma unroll
    for (int kc = 0; kc < 2; ++kc) {
      bf16x8 af[4], bfr[4];
#pragma unroll
      for (int m = 0; m < 4; ++m) {
        int row = wr * 64 + m * 16 + r16;
        unsigned off = ((unsigned)(row * 128 + (kc * 32 + g4 * 8) * 2)) ^ ((row & 7) << 4);
        af[m] = *(bf16x8*)((char*)As + off);
      }
#pragma unroll
      for (int n = 0; n < 4; ++n) {
        int row = wc * 64 + n * 16 + r16;
        unsigned off = ((unsigned)(row * 128 + (kc * 32 + g4 * 8) * 2)) ^ ((row & 7) << 4);
        bfr[n] = *(bf16x8*)((char*)Bs + off);
      }
#pragma unroll
      for (int m = 0; m < 4; ++m)
#pragma unroll
        for (int n = 0; n < 4; ++n)
          acc[m][n] = __builtin_amdgcn_mfma_f32_16x16x32_bf16(af[m], bfr[n], acc[m][n], 0, 0, 0);
    }
  }

#pragma unroll
  for (int n = 0; n < 4; ++n) {
    int col = col0 + wc * 64 + n * 16 + r16;
    float bv = bias[col];
#pragma unroll
    for (int m = 0; m < 4; ++m) {
      int rbase = row0 + wr * 64 + m * 16 + g4 * 4;
#pragma unroll
      for (int j = 0; j < 4; ++j)
        C[(size_t)(rbase + j) * MODEL_ + col] = acc[m][n][j] + bv;
    }
  }
}

extern "C" void kernel_launch(void* const* d_in, const int* in_sizes, int n_in,
                              void* d_out, int out_size, void* d_ws, size_t ws_size,
                              hipStream_t stream) {
  const float* q = (const float*)d_in[0];
  const float* k = (const float*)d_in[1];
  const float* v = (const float*)d_in[2];
  // d_in[3] = mask: faithfully unused (reference never applies it)
  const float* w_out = (const float*)d_in[4];
  const float* b_out = (const float*)d_in[5];
  float* out = (float*)d_out;

  // ws layout: [attn_bf 16.78MB][X region 33.55MB]
  //   X holds k_bf(4MB)+vt_bf(4MB) during attention, then w_bf (cvt AFTER attn).
  unsigned short* attn_bf = (unsigned short*)d_ws;
  unsigned short* xreg = attn_bf + (size_t)S_ * MODEL_;
  unsigned short* k_bf = xreg;
  unsigned short* vt_bf = xreg + (size_t)G_ * S_ * D_;
  unsigned short* w_bf = xreg;
  if (ws_size < ((size_t)S_ * MODEL_ + (size_t)MODEL_ * MODEL_) * 2) return;

  cvt_k_kernel<<<S_ * G_ * D_ / 4 / 256, 256, 0, stream>>>(k, k_bf);
  dim3 vg(S_ / 64, D_ / 32, G_);
  cvt_v_kernel<<<vg, 256, 0, stream>>>(v, vt_bf);

  dim3 ag(S_ / QB2, H_);
  attn32_kernel<<<ag, 512, 0, stream>>>(q, k_bf, vt_bf, attn_bf);

  cvt_f32_to_bf16<<<(MODEL_ * MODEL_ / 4) / 256, 256, 0, stream>>>(
      w_out, w_bf, MODEL_ * MODEL_ / 4);

  dim3 gg(MODEL_ / BN, S_ / BM);
  gemm_bt_bias<<<gg, 256, 0, stream>>>(attn_bf, w_bf, b_out, out);
}

// Round 10
// 198.707 us; speedup vs baseline: 1.4150x; 1.4150x over previous
//
#include <hip/hip_runtime.h>
#include <hip/hip_bf16.h>
#include <stdint.h>

// Problem constants
constexpr int S_ = 2048, H_ = 32, G_ = 8, HPG_ = 4, D_ = 128, MODEL_ = 4096;

typedef __attribute__((ext_vector_type(4))) float f32x4;
typedef __attribute__((ext_vector_type(16))) float f32x16;
typedef __attribute__((ext_vector_type(8))) short bf16x8;
typedef __attribute__((ext_vector_type(4))) short bf16x4;

__device__ inline unsigned short f2bf(float f) {
  unsigned u = __float_as_uint(f);
  u += 0x7FFFu + ((u >> 16) & 1u);   // round-to-nearest-even
  return (unsigned short)(u >> 16);
}

__device__ inline unsigned cvt_pk_bf16(float lo, float hi) {
  unsigned r;
  asm("v_cvt_pk_bf16_f32 %0, %1, %2" : "=v"(r) : "v"(lo), "v"(hi));
  return r;
}

__device__ inline void gload_lds16(const void* g, void* l) {
  __builtin_amdgcn_global_load_lds(
      (const __attribute__((address_space(1))) unsigned int*)g,
      (__attribute__((address_space(3))) unsigned int*)l,
      16, 0, 0);
}

// ---------------- w_out f32 -> bf16 (runs AFTER attn; aliases k/v region) ---
__global__ __launch_bounds__(256) void cvt_f32_to_bf16(
    const float* __restrict__ in, unsigned short* __restrict__ out, int n4) {
  int i = blockIdx.x * 256 + threadIdx.x;
  if (i < n4) {
    float4 v = reinterpret_cast<const float4*>(in)[i];
    bf16x4 o;
    o[0] = f2bf(v.x); o[1] = f2bf(v.y); o[2] = f2bf(v.z); o[3] = f2bf(v.w);
    reinterpret_cast<bf16x4*>(out)[i] = o;
  }
}

// ---------------- K: [S][G][D] f32 -> [G][S][D] bf16 ----------------
__global__ __launch_bounds__(256) void cvt_k_kernel(
    const float* __restrict__ in, unsigned short* __restrict__ out) {
  int i = blockIdx.x * 256 + threadIdx.x;   // over S*G*D/4
  int d4 = i & 31, g = (i >> 5) & 7, s = i >> 8;
  float4 v = reinterpret_cast<const float4*>(in)[i];
  bf16x4 o;
  o[0] = f2bf(v.x); o[1] = f2bf(v.y); o[2] = f2bf(v.z); o[3] = f2bf(v.w);
  reinterpret_cast<bf16x4*>(out)[(g * S_ + s) * 32 + d4] = o;
}

// ---------------- V: [S][G][D] f32 -> [G][D][S] bf16 (transpose) -----------
__global__ __launch_bounds__(256) void cvt_v_kernel(
    const float* __restrict__ in, unsigned short* __restrict__ out) {
  __shared__ float t[64][33];
  int s0 = blockIdx.x * 64, d0 = blockIdx.y * 32, g = blockIdx.z;
  int tid = threadIdx.x;
#pragma unroll
  for (int p = 0; p < 2; ++p) {
    int idx = p * 256 + tid;
    int s = idx >> 3, dq = (idx & 7) * 4;
    float4 v = *reinterpret_cast<const float4*>(
        in + ((size_t)(s0 + s) * G_ + g) * D_ + d0 + dq);
    t[s][dq] = v.x; t[s][dq + 1] = v.y; t[s][dq + 2] = v.z; t[s][dq + 3] = v.w;
  }
  __syncthreads();
  int d = tid >> 3, sq = (tid & 7) * 8;
  bf16x8 o;
#pragma unroll
  for (int j = 0; j < 8; ++j) o[j] = f2bf(t[sq + j][d]);
  *reinterpret_cast<bf16x8*>(out + ((size_t)g * D_ + d0 + d) * S_ + s0 + sq) = o;
}

// ---------------- flash attention, 8 waves, in-block KV-split ----------------
// grid (S/128, H), 512 threads. Waves 0-3: kv [0,1024); waves 4-7: kv [1024,2048).
// Wave (w&3) owns q rows qt*128 + (w&3)*32. Per group: KVB=32 double-buffered.
// S^T = K·Q^T (A=K LDS, B=Q regs); O^T += Vt·P^T (A=Vt LDS, B=P via permlane).
// Finish: group1 -> partial O f32 + (m,l) in LDS; group0 merges (exact f32).
// REGISTER BUDGET (R9 lesson): launch_bounds arg2 is min BLOCKS/CU on hipcc
// for non-256-thread blocks; (512,4) capped VGPR at 64 -> 240MB spill traffic.
// (512,2) + amdgpu_waves_per_eu(4) -> 128-reg cap = 4 waves/SIMD, need ~120.
constexpr int QB2 = 128, KVB = 32, NTG = 1024 / KVB;   // 32 tiles per group
constexpr float RTHR = 8.0f;   // defer-max threshold, log2 units

__global__ __launch_bounds__(512, 2) __attribute__((amdgpu_waves_per_eu(4)))
void attn32_kernel(
    const float* __restrict__ q, const unsigned short* __restrict__ kb,
    const unsigned short* __restrict__ vtb, unsigned short* __restrict__ aout) {
  // main: 2 groups x 2 bufs x 16KB = 64KB. epilogue: O1 f32 64KB + ml 1KB;
  // Ol (32KB) reuses [0,32KB) after merge. Total 65KB -> 2 blocks/CU.
  __shared__ __align__(16) char smem[66560];

  const int qt = blockIdx.x, h = blockIdx.y;
  const int g = h >> 2;   // HPG = 4
  const int tid = threadIdx.x, w = tid >> 6, lane = tid & 63;
  const int l31 = lane & 31, hi = lane >> 5;
  const int gsel = w >> 2, wq = w & 3;

  // ---- Q B-frags (scale * log2e folded in): qf[c] d = c*16 + hi*8 + e ----
  const float scale2 = 0.12751742354783493f;  // (1/sqrt(128)) * log2(e)
  bf16x8 qf[8];
  {
    const int qrow = qt * QB2 + wq * 32 + l31;
    const float* qp = q + ((size_t)qrow * H_ + h) * D_;
#pragma unroll
    for (int c = 0; c < 8; ++c) {
      const float* p0 = qp + c * 16 + hi * 8;
      float4 a = *(const float4*)p0;
      float4 b = *(const float4*)(p0 + 4);
      bf16x8 f;
      f[0] = f2bf(a.x * scale2); f[1] = f2bf(a.y * scale2);
      f[2] = f2bf(a.z * scale2); f[3] = f2bf(a.w * scale2);
      f[4] = f2bf(b.x * scale2); f[5] = f2bf(b.y * scale2);
      f[6] = f2bf(b.z * scale2); f[7] = f2bf(b.w * scale2);
      qf[c] = f;
    }
  }

  // ---- staging sources as base POINTERS (saves index regs) ----
  // K 8KB: phys p -> kv = p>>8, log col byte = (p&255) ^ ((kv&15)<<4)
  // V 8KB: phys p -> R = p>>8 (R = d>>2), il = (p&255) ^ ((R&7)<<4),
  //        d = R*4 + (il>>6), kv = (il&63)>>1
  const unsigned short* pK[2];
  const unsigned short* pV[2];
  int vkv[2];
  {
    const unsigned short* kg = kb + (size_t)g * S_ * D_;
    const unsigned short* vg = vtb + (size_t)g * D_ * S_;
#pragma unroll
    for (int j = 0; j < 2; ++j) {
      int p = (wq * 2 + j) * 1024 + lane * 16;
      int kvr = p >> 8;
      pK[j] = kg + (size_t)(gsel * 1024 + kvr) * D_ +
              (((p & 255) ^ ((kvr & 15) << 4)) >> 1);
      int R = p >> 8;
      int il = (p & 255) ^ ((R & 7) << 4);
      pV[j] = vg + (size_t)(R * 4 + (il >> 6)) * S_ + gsel * 1024;
      vkv[j] = (il & 63) >> 1;
    }
  }

  auto stage = [&](int t) {
    int kv0 = t * KVB;
    char* base = smem + (gsel * 2 + (t & 1)) * 16384;
#pragma unroll
    for (int j = 0; j < 2; ++j) {
      gload_lds16(pK[j] + (size_t)kv0 * D_, base + (wq * 2 + j) * 1024);
      gload_lds16(pV[j] + kv0 + vkv[j], base + 8192 + (wq * 2 + j) * 1024);
    }
  };

  f32x16 of[4];
#pragma unroll
  for (int i = 0; i < 4; ++i) of[i] = (f32x16)0.f;
  float m = -1e30f, l = 0.f;

  // ---- prologue ----
  stage(0);
  asm volatile("s_waitcnt vmcnt(0)" ::: "memory");
  __builtin_amdgcn_s_barrier();

  // ---- main loop: stage(t+1) first, then compute(t); 1 barrier/tile ----
  for (int t = 0; t < NTG; ++t) {
    if (t + 1 < NTG) stage(t + 1);

    const char* Kd = smem + (gsel * 2 + (t & 1)) * 16384;
    const char* Vd = Kd + 8192;

    // ---- QK^T: S^T[kv][q], single accumulator (reg-lean; TLP feeds pipe) ----
    f32x16 sv = (f32x16)0.f;
    __builtin_amdgcn_s_setprio(1);
#pragma unroll
    for (int c = 0; c < 8; ++c) {
      unsigned off = (unsigned)(l31 * 256) +
                     (((unsigned)(c * 32 + hi * 16)) ^ ((unsigned)(l31 & 15) << 4));
      bf16x8 kf = *(const bf16x8*)(Kd + off);
      sv = __builtin_amdgcn_mfma_f32_32x32x16_bf16(kf, qf[c], sv, 0, 0, 0);
    }
    __builtin_amdgcn_s_setprio(0);
    // rows: kv = (r&3) + 8*(r>>2) + 4*hi; col q = l31

    // ---- online softmax (exp2 domain; expression-tree max, no arrays) ----
    float tmax = fmaxf(
        fmaxf(fmaxf(fmaxf(sv[0], sv[8]), fmaxf(sv[4], sv[12])),
              fmaxf(fmaxf(sv[1], sv[9]), fmaxf(sv[5], sv[13]))),
        fmaxf(fmaxf(fmaxf(sv[2], sv[10]), fmaxf(sv[6], sv[14])),
              fmaxf(fmaxf(sv[3], sv[11]), fmaxf(sv[7], sv[15]))));
    tmax = fmaxf(tmax, __shfl_xor(tmax, 32));
    if (__any(tmax > m + RTHR)) {
      float mnew = fmaxf(m, tmax);
      float alpha = __builtin_exp2f(m - mnew);
#pragma unroll
      for (int i = 0; i < 4; ++i)
#pragma unroll
        for (int r = 0; r < 16; ++r) of[i][r] *= alpha;
      l *= alpha;
      m = mnew;
    }
    // fused exp2 + sum + pack (pv never a live array)
    unsigned pk[8];
    float sum = 0.f;
#pragma unroll
    for (int b = 0; b < 8; ++b) {
      float p0 = __builtin_exp2f(sv[2 * b] - m);
      float p1 = __builtin_exp2f(sv[2 * b + 1] - m);
      sum += p0 + p1;
      pk[b] = cvt_pk_bf16(p0, p1);
    }
    sum += __shfl_xor(sum, 32);
    l += sum;

    // ---- P -> B-frags: permlane32_swap gathers lows/highs ----
    bf16x8 pf[2];
#pragma unroll
    for (int kc = 0; kc < 2; ++kc) {
      auto sA = __builtin_amdgcn_permlane32_swap(pk[kc * 4 + 0], pk[kc * 4 + 2],
                                                 false, false);
      auto sB = __builtin_amdgcn_permlane32_swap(pk[kc * 4 + 1], pk[kc * 4 + 3],
                                                 false, false);
      unsigned fr[4] = {(unsigned)sA[0], (unsigned)sB[0],
                        (unsigned)sA[1], (unsigned)sB[1]};
      __builtin_memcpy(&pf[kc], fr, 16);
    }

    // ---- PV: O^T[d][q] += Vt·P^T, 4 independent chains ----
    __builtin_amdgcn_s_setprio(1);
#pragma unroll
    for (int db = 0; db < 4; ++db) {
      int R = db * 8 + (l31 >> 2);
      unsigned lg = (unsigned)((l31 & 3) * 64);
#pragma unroll
      for (int kc = 0; kc < 2; ++kc) {
        unsigned off = (unsigned)(R * 256) +
                       ((lg + (unsigned)(kc * 32 + hi * 16)) ^ ((unsigned)(R & 7) << 4));
        bf16x8 vf = *(const bf16x8*)(Vd + off);
        of[db] = __builtin_amdgcn_mfma_f32_32x32x16_bf16(vf, pf[kc], of[db], 0, 0, 0);
      }
    }
    __builtin_amdgcn_s_setprio(0);

    asm volatile("s_waitcnt vmcnt(0)" ::: "memory");
    __builtin_amdgcn_s_barrier();
  }

  // ---- combine: group1 publishes partial O (f32) + (m,l); group0 merges ----
  float* O1 = (float*)smem;                    // 4 waves x 16KB = 64KB
  float* ml = (float*)(smem + 65536);          // [4 wq][32 q][2]
  if (w >= 4) {
    float* reg = O1 + (w - 4) * 4096;          // [128 d][32 q] f32
#pragma unroll
    for (int db = 0; db < 4; ++db)
#pragma unroll
      for (int r = 0; r < 16; ++r) {
        int dd = db * 32 + (r & 3) + 8 * (r >> 2) + 4 * hi;
        reg[dd * 32 + l31] = of[db][r];
      }
    if (!hi) { ml[wq * 64 + l31 * 2] = m; ml[wq * 64 + l31 * 2 + 1] = l; }
  }
  __syncthreads();
  float inv = 0.f;
  if (w < 4) {
    float m1 = ml[wq * 64 + l31 * 2], l1 = ml[wq * 64 + l31 * 2 + 1];
    float mf = fmaxf(m, m1);
    float a0 = __builtin_exp2f(m - mf), a1 = __builtin_exp2f(m1 - mf);
    inv = 1.0f / (l * a0 + l1 * a1);
    const float* reg = O1 + wq * 4096;
#pragma unroll
    for (int db = 0; db < 4; ++db)
#pragma unroll
      for (int r = 0; r < 16; ++r) {
        int dd = db * 32 + (r & 3) + 8 * (r >> 2) + 4 * hi;
        of[db][r] = of[db][r] * a0 + reg[dd * 32 + l31] * a1;
      }
  }
  __syncthreads();

  // ---- epilogue: normalize, transpose via LDS (Ol reuses [0,32KB)) ----
  unsigned short* Ol = (unsigned short*)smem;  // [128 q][128 d] bf16 = 32KB
  if (w < 4) {
    const int ql = wq * 32 + l31;
#pragma unroll
    for (int db = 0; db < 4; ++db)
#pragma unroll
      for (int rp = 0; rp < 8; ++rp) {
        int r0 = rp * 2;
        int d0 = db * 32 + (r0 & 3) + 8 * (r0 >> 2) + 4 * hi;
        unsigned pkv = cvt_pk_bf16(of[db][r0] * inv, of[db][r0 + 1] * inv);
        unsigned off = ((unsigned)(ql * 256 + d0 * 2)) ^ ((unsigned)(ql & 7) << 4);
        *(unsigned*)((char*)Ol + off) = pkv;
      }
  }
  __syncthreads();
  const size_t obase = ((size_t)qt * QB2) * MODEL_ + (size_t)h * D_;
#pragma unroll
  for (int pass = 0; pass < 4; ++pass) {
    int row = pass * 32 + (tid >> 4);
    int c = tid & 15;
    unsigned off = ((unsigned)(row * 256 + c * 16)) ^ ((unsigned)(row & 7) << 4);
    bf16x8 vv = *(const bf16x8*)((char*)Ol + off);
    *(bf16x8*)(aout + obase + (size_t)row * MODEL_ + c * 8) = vv;
  }
}

// ---------------- out-projection GEMM: C = A @ B^T + bias (m97 structure) ----
constexpr int BM = 128, BN = 128, BK = 64;

__global__ __launch_bounds__(256, 2) void gemm_bt_bias(
    const unsigned short* __restrict__ A, const unsigned short* __restrict__ B,
    const float* __restrict__ bias, float* __restrict__ C) {
  __shared__ unsigned short As[BM * BK];
  __shared__ unsigned short Bs[BN * BK];

  const int tid = threadIdx.x;
  const int w = tid >> 6, lane = tid & 63;
  const int wr = w >> 1, wc = w & 1;
  const int r16 = lane & 15, g4 = lane >> 4;
  const int row0 = blockIdx.y * BM, col0 = blockIdx.x * BN;

  f32x4 acc[4][4];
#pragma unroll
  for (int m = 0; m < 4; ++m)
#pragma unroll
    for (int n = 0; n < 4; ++n) acc[m][n] = (f32x4)0.f;

  for (int kt = 0; kt < MODEL_ / BK; ++kt) {
    const int k0 = kt * BK;
    __syncthreads();
#pragma unroll
    for (int j = 0; j < 4; ++j) {
      int chunk = w * 4 + j;
      int sb = chunk * 1024 + lane * 16;
      int srow = sb >> 7;
      int lb = sb ^ ((srow & 7) << 4);
      int kk = (lb & 127) >> 1;
      gload_lds16(A + (size_t)(row0 + srow) * MODEL_ + k0 + kk,
                  (char*)As + chunk * 1024);
      gload_lds16(B + (size_t)(col0 + srow) * MODEL_ + k0 + kk,
                  (char*)Bs + chunk * 1024);
    }
    asm volatile("s_waitcnt vmcnt(0)" ::: "memory");
    __syncthreads();

#pragma unroll
    for (int kc = 0; kc < 2; ++kc) {
      bf16x8 af[4], bfr[4];
#pragma unroll
      for (int m = 0; m < 4; ++m) {
        int row = wr * 64 + m * 16 + r16;
        unsigned off = ((unsigned)(row * 128 + (kc * 32 + g4 * 8) * 2)) ^ ((row & 7) << 4);
        af[m] = *(bf16x8*)((char*)As + off);
      }
#pragma unroll
      for (int n = 0; n < 4; ++n) {
        int row = wc * 64 + n * 16 + r16;
        unsigned off = ((unsigned)(row * 128 + (kc * 32 + g4 * 8) * 2)) ^ ((row & 7) << 4);
        bfr[n] = *(bf16x8*)((char*)Bs + off);
      }
#pragma unroll
      for (int m = 0; m < 4; ++m)
#pragma unroll
        for (int n = 0; n < 4; ++n)
          acc[m][n] = __builtin_amdgcn_mfma_f32_16x16x32_bf16(af[m], bfr[n], acc[m][n], 0, 0, 0);
    }
  }

#pragma unroll
  for (int n = 0; n < 4; ++n) {
    int col = col0 + wc * 64 + n * 16 + r16;
    float bv = bias[col];
#pragma unroll
    for (int m = 0; m < 4; ++m) {
      int rbase = row0 + wr * 64 + m * 16 + g4 * 4;
#pragma unroll
      for (int j = 0; j < 4; ++j)
        C[(size_t)(rbase + j) * MODEL_ + col] = acc[m][n][j] + bv;
    }
  }
}

extern "C" void kernel_launch(void* const* d_in, const int* in_sizes, int n_in,
                              void* d_out, int out_size, void* d_ws, size_t ws_size,
                              hipStream_t stream) {
  const float* q = (const float*)d_in[0];
  const float* k = (const float*)d_in[1];
  const float* v = (const float*)d_in[2];
  // d_in[3] = mask: faithfully unused (reference never applies it)
  const float* w_out = (const float*)d_in[4];
  const float* b_out = (const float*)d_in[5];
  float* out = (float*)d_out;

  // ws layout: [attn_bf 16.78MB][X region 33.55MB]
  //   X holds k_bf(4MB)+vt_bf(4MB) during attention, then w_bf (cvt AFTER attn).
  unsigned short* attn_bf = (unsigned short*)d_ws;
  unsigned short* xreg = attn_bf + (size_t)S_ * MODEL_;
  unsigned short* k_bf = xreg;
  unsigned short* vt_bf = xreg + (size_t)G_ * S_ * D_;
  unsigned short* w_bf = xreg;
  if (ws_size < ((size_t)S_ * MODEL_ + (size_t)MODEL_ * MODEL_) * 2) return;

  cvt_k_kernel<<<S_ * G_ * D_ / 4 / 256, 256, 0, stream>>>(k, k_bf);
  dim3 vg(S_ / 64, D_ / 32, G_);
  cvt_v_kernel<<<vg, 256, 0, stream>>>(v, vt_bf);

  dim3 ag(S_ / QB2, H_);
  attn32_kernel<<<ag, 512, 0, stream>>>(q, k_bf, vt_bf, attn_bf);

  cvt_f32_to_bf16<<<(MODEL_ * MODEL_ / 4) / 256, 256, 0, stream>>>(
      w_out, w_bf, MODEL_ * MODEL_ / 4);

  dim3 gg(MODEL_ / BN, S_ / BM);
  gemm_bt_bias<<<gg, 256, 0, stream>>>(attn_bf, w_bf, b_out, out);
}

// Round 11
// 192.660 us; speedup vs baseline: 1.4594x; 1.0314x over previous
//
#include <hip/hip_runtime.h>
#include <hip/hip_bf16.h>
#include <stdint.h>

// Problem constants
constexpr int S_ = 2048, H_ = 32, G_ = 8, HPG_ = 4, D_ = 128, MODEL_ = 4096;

typedef __attribute__((ext_vector_type(4))) float f32x4;
typedef __attribute__((ext_vector_type(16))) float f32x16;
typedef __attribute__((ext_vector_type(8))) short bf16x8;
typedef __attribute__((ext_vector_type(4))) short bf16x4;

__device__ inline unsigned short f2bf(float f) {
  unsigned u = __float_as_uint(f);
  u += 0x7FFFu + ((u >> 16) & 1u);   // round-to-nearest-even
  return (unsigned short)(u >> 16);
}

__device__ inline unsigned cvt_pk_bf16(float lo, float hi) {
  unsigned r;
  asm("v_cvt_pk_bf16_f32 %0, %1, %2" : "=v"(r) : "v"(lo), "v"(hi));
  return r;
}

__device__ inline void gload_lds16(const void* g, void* l) {
  __builtin_amdgcn_global_load_lds(
      (const __attribute__((address_space(1))) unsigned int*)g,
      (__attribute__((address_space(3))) unsigned int*)l,
      16, 0, 0);
}

// ---------------- w_out f32 -> bf16 (runs AFTER attn; aliases k/v region) ---
__global__ __launch_bounds__(256) void cvt_f32_to_bf16(
    const float* __restrict__ in, unsigned short* __restrict__ out, int n4) {
  int i = blockIdx.x * 256 + threadIdx.x;
  if (i < n4) {
    float4 v = reinterpret_cast<const float4*>(in)[i];
    bf16x4 o;
    o[0] = f2bf(v.x); o[1] = f2bf(v.y); o[2] = f2bf(v.z); o[3] = f2bf(v.w);
    reinterpret_cast<bf16x4*>(out)[i] = o;
  }
}

// ---------------- K: [S][G][D] f32 -> [G][S][D] bf16 ----------------
__global__ __launch_bounds__(256) void cvt_k_kernel(
    const float* __restrict__ in, unsigned short* __restrict__ out) {
  int i = blockIdx.x * 256 + threadIdx.x;   // over S*G*D/4
  int d4 = i & 31, g = (i >> 5) & 7, s = i >> 8;
  float4 v = reinterpret_cast<const float4*>(in)[i];
  bf16x4 o;
  o[0] = f2bf(v.x); o[1] = f2bf(v.y); o[2] = f2bf(v.z); o[3] = f2bf(v.w);
  reinterpret_cast<bf16x4*>(out)[(g * S_ + s) * 32 + d4] = o;
}

// ---------------- V: [S][G][D] f32 -> [G][D][S] bf16 (transpose) -----------
__global__ __launch_bounds__(256) void cvt_v_kernel(
    const float* __restrict__ in, unsigned short* __restrict__ out) {
  __shared__ float t[64][33];
  int s0 = blockIdx.x * 64, d0 = blockIdx.y * 32, g = blockIdx.z;
  int tid = threadIdx.x;
#pragma unroll
  for (int p = 0; p < 2; ++p) {
    int idx = p * 256 + tid;
    int s = idx >> 3, dq = (idx & 7) * 4;
    float4 v = *reinterpret_cast<const float4*>(
        in + ((size_t)(s0 + s) * G_ + g) * D_ + d0 + dq);
    t[s][dq] = v.x; t[s][dq + 1] = v.y; t[s][dq + 2] = v.z; t[s][dq + 3] = v.w;
  }
  __syncthreads();
  int d = tid >> 3, sq = (tid & 7) * 8;
  bf16x8 o;
#pragma unroll
  for (int j = 0; j < 8; ++j) o[j] = f2bf(t[sq + j][d]);
  *reinterpret_cast<bf16x8*>(out + ((size_t)g * D_ + d0 + d) * S_ + s0 + sq) = o;
}

// ---------------- flash attention, 32x32 MFMA, swapped operands ----------------
// grid (S/128, H), 256 threads / 4 waves; wave w owns q rows qt*128+w*32.
// R4's proven cadence (3-buffer, counted vmcnt(4), one barrier/tile) +
// R10's conflict-free swizzles + lean fused softmax (exp2 domain).
// OCCUPANCY TARGET: 3 blocks/CU = 3 waves/SIMD. Requires total regs <= 170
// (launch_bounds(256,3)) and LDS 48KB (3 blocks x 48 = 144 <= 160KB).
// K tile [32 kv][128 d] bf16 8KB, swizzle (kv&15)<<4 -> QK reads 2-way (free).
// V tile: R = d>>2 rows of 256B (4 d x 32 kv), swizzle (R&7)<<4 -> ~none.
constexpr int QB2 = 128, KVB = 32, NT = S_ / KVB;   // 64 tiles
constexpr float RTHR = 8.0f;   // defer-max threshold, log2 units (P <= 256)

__global__ __launch_bounds__(256, 3) void attn32_kernel(
    const float* __restrict__ q, const unsigned short* __restrict__ kb,
    const unsigned short* __restrict__ vtb, unsigned short* __restrict__ aout) {
  // 3 buffers x (K 8KB + V 8KB) = 48KB; epilogue Ol reuses first 32KB.
  __shared__ __align__(16) char smem[49152];

  const int qt = blockIdx.x, h = blockIdx.y;
  const int g = h >> 2;   // HPG = 4
  const int tid = threadIdx.x, w = tid >> 6, lane = tid & 63;
  const int l31 = lane & 31, hi = lane >> 5;

  // ---- Q B-frags (scale * log2e folded in): qf[c] d = c*16 + hi*8 + e ----
  const float scale2 = 0.12751742354783493f;  // (1/sqrt(128)) * log2(e)
  bf16x8 qf[8];
  {
    const int qrow = qt * QB2 + w * 32 + l31;
    const float* qp = q + ((size_t)qrow * H_ + h) * D_;
#pragma unroll
    for (int c = 0; c < 8; ++c) {
      const float* p0 = qp + c * 16 + hi * 8;
      float4 a = *(const float4*)p0;
      float4 b = *(const float4*)(p0 + 4);
      bf16x8 f;
      f[0] = f2bf(a.x * scale2); f[1] = f2bf(a.y * scale2);
      f[2] = f2bf(a.z * scale2); f[3] = f2bf(a.w * scale2);
      f[4] = f2bf(b.x * scale2); f[5] = f2bf(b.y * scale2);
      f[6] = f2bf(b.z * scale2); f[7] = f2bf(b.w * scale2);
      qf[c] = f;
    }
  }

  // ---- staging sources as base POINTERS (pre-swizzled; linear LDS dest) ----
  // K 8KB: phys p -> kv = p>>8, log col byte = (p&255) ^ ((kv&15)<<4)
  // V 8KB: phys p -> R = p>>8, il = (p&255) ^ ((R&7)<<4),
  //        d = R*4 + (il>>6), kv = (il&63)>>1
  const unsigned short* pK[2];
  const unsigned short* pV[2];
  {
    const unsigned short* kg = kb + (size_t)g * S_ * D_;
    const unsigned short* vg = vtb + (size_t)g * D_ * S_;
#pragma unroll
    for (int j = 0; j < 2; ++j) {
      int p = (w * 2 + j) * 1024 + lane * 16;
      int kvr = p >> 8;
      pK[j] = kg + (size_t)kvr * D_ + (((p & 255) ^ ((kvr & 15) << 4)) >> 1);
      int R = p >> 8;
      int il = (p & 255) ^ ((R & 7) << 4);
      pV[j] = vg + (size_t)(R * 4 + (il >> 6)) * S_ + ((il & 63) >> 1);
    }
  }

  auto stage = [&](int t) {
    int kv0 = t * KVB;
    char* base = smem + (t % 3) * 16384;
#pragma unroll
    for (int j = 0; j < 2; ++j) {
      gload_lds16(pK[j] + (size_t)kv0 * D_, base + (w * 2 + j) * 1024);
      gload_lds16(pV[j] + kv0, base + 8192 + (w * 2 + j) * 1024);
    }
  };

  f32x16 of[4];
#pragma unroll
  for (int i = 0; i < 4; ++i) of[i] = (f32x16)0.f;
  float m = -1e30f, l = 0.f;

  // ---- prologue: two tiles in flight ----
  stage(0);
  stage(1);

  // ---- main loop: counted vmcnt(4) keeps stage(t+1) in flight ----
  for (int t = 0; t < NT; ++t) {
    if (t + 1 < NT) asm volatile("s_waitcnt vmcnt(4)" ::: "memory");
    else            asm volatile("s_waitcnt vmcnt(0)" ::: "memory");
    __builtin_amdgcn_s_barrier();
    if (t + 2 < NT) stage(t + 2);

    const char* Kd = smem + (t % 3) * 16384;
    const char* Vd = Kd + 8192;

    // ---- QK^T: S^T[kv][q], two independent 4-deep chains ----
    f32x16 s0 = (f32x16)0.f, s1 = (f32x16)0.f;
    __builtin_amdgcn_s_setprio(1);
#pragma unroll
    for (int c = 0; c < 8; ++c) {
      unsigned off = (unsigned)(l31 * 256) +
                     (((unsigned)(c * 32 + hi * 16)) ^ ((unsigned)(l31 & 15) << 4));
      bf16x8 kf = *(const bf16x8*)(Kd + off);
      if (c & 1)
        s1 = __builtin_amdgcn_mfma_f32_32x32x16_bf16(kf, qf[c], s1, 0, 0, 0);
      else
        s0 = __builtin_amdgcn_mfma_f32_32x32x16_bf16(kf, qf[c], s0, 0, 0, 0);
    }
    __builtin_amdgcn_s_setprio(0);
    f32x16 sv = s0 + s1;   // rows: kv = (r&3) + 8*(r>>2) + 4*hi; col q = l31

    // ---- online softmax (exp2 domain; expression-tree max, no arrays) ----
    float tmax = fmaxf(
        fmaxf(fmaxf(fmaxf(sv[0], sv[8]), fmaxf(sv[4], sv[12])),
              fmaxf(fmaxf(sv[1], sv[9]), fmaxf(sv[5], sv[13]))),
        fmaxf(fmaxf(fmaxf(sv[2], sv[10]), fmaxf(sv[6], sv[14])),
              fmaxf(fmaxf(sv[3], sv[11]), fmaxf(sv[7], sv[15]))));
    tmax = fmaxf(tmax, __shfl_xor(tmax, 32));
    if (__any(tmax > m + RTHR)) {
      float mnew = fmaxf(m, tmax);
      float alpha = __builtin_exp2f(m - mnew);
#pragma unroll
      for (int i = 0; i < 4; ++i)
#pragma unroll
        for (int r = 0; r < 16; ++r) of[i][r] *= alpha;
      l *= alpha;
      m = mnew;
    }
    // fused exp2 + sum + pack (pv never a live array)
    unsigned pk[8];
    float sum = 0.f;
#pragma unroll
    for (int b = 0; b < 8; ++b) {
      float p0 = __builtin_exp2f(sv[2 * b] - m);
      float p1 = __builtin_exp2f(sv[2 * b + 1] - m);
      sum += p0 + p1;
      pk[b] = cvt_pk_bf16(p0, p1);
    }
    sum += __shfl_xor(sum, 32);
    l += sum;

    // ---- P -> B-frags: permlane32_swap gathers lows/highs ----
    bf16x8 pf[2];
#pragma unroll
    for (int kc = 0; kc < 2; ++kc) {
      auto sA = __builtin_amdgcn_permlane32_swap(pk[kc * 4 + 0], pk[kc * 4 + 2],
                                                 false, false);
      auto sB = __builtin_amdgcn_permlane32_swap(pk[kc * 4 + 1], pk[kc * 4 + 3],
                                                 false, false);
      unsigned fr[4] = {(unsigned)sA[0], (unsigned)sB[0],
                        (unsigned)sA[1], (unsigned)sB[1]};
      __builtin_memcpy(&pf[kc], fr, 16);
    }

    // ---- PV: O^T[d][q] += Vt·P^T, 4 independent chains ----
    __builtin_amdgcn_s_setprio(1);
#pragma unroll
    for (int db = 0; db < 4; ++db) {
      int R = db * 8 + (l31 >> 2);
      unsigned lg = (unsigned)((l31 & 3) * 64);
#pragma unroll
      for (int kc = 0; kc < 2; ++kc) {
        unsigned off = (unsigned)(R * 256) +
                       ((lg + (unsigned)(kc * 32 + hi * 16)) ^ ((unsigned)(R & 7) << 4));
        bf16x8 vf = *(const bf16x8*)(Vd + off);
        of[db] = __builtin_amdgcn_mfma_f32_32x32x16_bf16(vf, pf[kc], of[db], 0, 0, 0);
      }
    }
    __builtin_amdgcn_s_setprio(0);
  }

  // ---- epilogue: normalize, transpose via LDS, coalesced bf16 store ----
  __syncthreads();   // all waves done with PV reads before Ol overwrites bufs
  float inv = 1.0f / l;
  unsigned short* Ol = (unsigned short*)smem;   // [128 q][128 d] bf16 = 32KB
  const int ql = w * 32 + l31;
#pragma unroll
  for (int db = 0; db < 4; ++db) {
#pragma unroll
    for (int rp = 0; rp < 8; ++rp) {
      int r0 = rp * 2;
      int d0 = db * 32 + (r0 & 3) + 8 * (r0 >> 2) + 4 * hi;  // d0 even, d0+1 next
      unsigned pkv = cvt_pk_bf16(of[db][r0] * inv, of[db][r0 + 1] * inv);
      unsigned off = ((unsigned)(ql * 256 + d0 * 2)) ^ ((unsigned)(ql & 7) << 4);
      *(unsigned*)((char*)Ol + off) = pkv;
    }
  }
  __syncthreads();
  const size_t obase = ((size_t)qt * QB2) * MODEL_ + (size_t)h * D_;
#pragma unroll
  for (int pass = 0; pass < 8; ++pass) {
    int row = pass * 16 + (tid >> 4);
    int c = tid & 15;
    unsigned off = ((unsigned)(row * 256 + c * 16)) ^ ((unsigned)(row & 7) << 4);
    bf16x8 vv = *(const bf16x8*)((char*)Ol + off);
    *(bf16x8*)(aout + obase + (size_t)row * MODEL_ + c * 8) = vv;
  }
}

// ---------------- out-projection GEMM: C = A @ B^T + bias (m97 structure) ----
// T1 XCD swizzle: 1D grid of 512; lin = (id%8)*64 + id/8 gives each XCD a
// contiguous 64-block range; column-major decomposition (by = lin%16) makes
// each XCD's 4 B col-panels (4MB) L2-resident; A (16MB) streams via L3.
constexpr int BM = 128, BN = 128, BK = 64;

__global__ __launch_bounds__(256, 2) void gemm_bt_bias(
    const unsigned short* __restrict__ A, const unsigned short* __restrict__ B,
    const float* __restrict__ bias, float* __restrict__ C) {
  __shared__ unsigned short As[BM * BK];
  __shared__ unsigned short Bs[BN * BK];

  const int tid = threadIdx.x;
  const int w = tid >> 6, lane = tid & 63;
  const int wr = w >> 1, wc = w & 1;
  const int r16 = lane & 15, g4 = lane >> 4;
  const int id = blockIdx.x;
  const int lin = (id & 7) * 64 + (id >> 3);
  const int row0 = (lin & 15) * BM, col0 = (lin >> 4) * BN;

  f32x4 acc[4][4];
#pragma unroll
  for (int m = 0; m < 4; ++m)
#pragma unroll
    for (int n = 0; n < 4; ++n) acc[m][n] = (f32x4)0.f;

  for (int kt = 0; kt < MODEL_ / BK; ++kt) {
    const int k0 = kt * BK;
    __syncthreads();
#pragma unroll
    for (int j = 0; j < 4; ++j) {
      int chunk = w * 4 + j;
      int sb = chunk * 1024 + lane * 16;
      int srow = sb >> 7;
      int lb = sb ^ ((srow & 7) << 4);
      int kk = (lb & 127) >> 1;
      gload_lds16(A + (size_t)(row0 + srow) * MODEL_ + k0 + kk,
                  (char*)As + chunk * 1024);
      gload_lds16(B + (size_t)(col0 + srow) * MODEL_ + k0 + kk,
                  (char*)Bs + chunk * 1024);
    }
    asm volatile("s_waitcnt vmcnt(0)" ::: "memory");
    __syncthreads();

#pragma unroll
    for (int kc = 0; kc < 2; ++kc) {
      bf16x8 af[4], bfr[4];
#pragma unroll
      for (int m = 0; m < 4; ++m) {
        int row = wr * 64 + m * 16 + r16;
        unsigned off = ((unsigned)(row * 128 + (kc * 32 + g4 * 8) * 2)) ^ ((row & 7) << 4);
        af[m] = *(bf16x8*)((char*)As + off);
      }
#pragma unroll
      for (int n = 0; n < 4; ++n) {
        int row = wc * 64 + n * 16 + r16;
        unsigned off = ((unsigned)(row * 128 + (kc * 32 + g4 * 8) * 2)) ^ ((row & 7) << 4);
        bfr[n] = *(bf16x8*)((char*)Bs + off);
      }
#pragma unroll
      for (int m = 0; m < 4; ++m)
#pragma unroll
        for (int n = 0; n < 4; ++n)
          acc[m][n] = __builtin_amdgcn_mfma_f32_16x16x32_bf16(af[m], bfr[n], acc[m][n], 0, 0, 0);
    }
  }

#pragma unroll
  for (int n = 0; n < 4; ++n) {
    int col = col0 + wc * 64 + n * 16 + r16;
    float bv = bias[col];
#pragma unroll
    for (int m = 0; m < 4; ++m) {
      int rbase = row0 + wr * 64 + m * 16 + g4 * 4;
#pragma unroll
      for (int j = 0; j < 4; ++j)
        C[(size_t)(rbase + j) * MODEL_ + col] = acc[m][n][j] + bv;
    }
  }
}

extern "C" void kernel_launch(void* const* d_in, const int* in_sizes, int n_in,
                              void* d_out, int out_size, void* d_ws, size_t ws_size,
                              hipStream_t stream) {
  const float* q = (const float*)d_in[0];
  const float* k = (const float*)d_in[1];
  const float* v = (const float*)d_in[2];
  // d_in[3] = mask: faithfully unused (reference never applies it)
  const float* w_out = (const float*)d_in[4];
  const float* b_out = (const float*)d_in[5];
  float* out = (float*)d_out;

  // ws layout: [attn_bf 16.78MB][X region 33.55MB]
  //   X holds k_bf(4MB)+vt_bf(4MB) during attention, then w_bf (cvt AFTER attn).
  unsigned short* attn_bf = (unsigned short*)d_ws;
  unsigned short* xreg = attn_bf + (size_t)S_ * MODEL_;
  unsigned short* k_bf = xreg;
  unsigned short* vt_bf = xreg + (size_t)G_ * S_ * D_;
  unsigned short* w_bf = xreg;
  if (ws_size < ((size_t)S_ * MODEL_ + (size_t)MODEL_ * MODEL_) * 2) return;

  cvt_k_kernel<<<S_ * G_ * D_ / 4 / 256, 256, 0, stream>>>(k, k_bf);
  dim3 vg(S_ / 64, D_ / 32, G_);
  cvt_v_kernel<<<vg, 256, 0, stream>>>(v, vt_bf);

  dim3 ag(S_ / QB2, H_);
  attn32_kernel<<<ag, 256, 0, stream>>>(q, k_bf, vt_bf, attn_bf);

  cvt_f32_to_bf16<<<(MODEL_ * MODEL_ / 4) / 256, 256, 0, stream>>>(
      w_out, w_bf, MODEL_ * MODEL_ / 4);

  gemm_bt_bias<<<512, 256, 0, stream>>>(attn_bf, w_bf, b_out, out);
}